// Round 3
// baseline (2407.804 us; speedup 1.0000x reference)
//
#include <hip/hip_runtime.h>
#include <hip/hip_bf16.h>
#include <math.h>

#define NNODES 100000
#define NREL 4
#define NEDGE 200000
#define NH 8
#define FDIM 512

typedef float f4 __attribute__((ext_vector_type(4)));
typedef __bf16 bf16x8 __attribute__((ext_vector_type(8)));
typedef __bf16 bf16x4 __attribute__((ext_vector_type(4)));

__device__ __forceinline__ float eluf(float v) { return v > 0.f ? v : expm1f(v); }

// ---- f32 -> bf16 convert (n multiple of 1024) ----
__global__ void k_conv(const float* __restrict__ in, __bf16* __restrict__ outp) {
  int i = (blockIdx.x * 256 + threadIdx.x) * 4;
  f4 v = *(const f4*)(in + i);
  bf16x4 o = {(__bf16)v.x, (__bf16)v.y, (__bf16)v.z, (__bf16)v.w};
  *(bf16x4*)(outp + i) = o;
}
// ---- bf16 -> bf16 copy variant (acc bf16 path) ----
__global__ void k_copyb(const __bf16* __restrict__ in, __bf16* __restrict__ outp) {
  int i = (blockIdx.x * 256 + threadIdx.x) * 8;
  *(bf16x8*)(outp + i) = *(const bf16x8*)(in + i);
}

// ---- W [R,K,512] f32 -> Wt [R,512,K] bf16 ----
__global__ void k_transW(const float* __restrict__ W, __bf16* __restrict__ Wt, int K) {
  __shared__ float tile[32][33];
  int r = blockIdx.z;
  const float* Wr = W + (size_t)r * K * FDIM;
  __bf16* Wtr = Wt + (size_t)r * FDIM * K;
  int k0 = blockIdx.x * 32, n0 = blockIdx.y * 32;
  int tx = threadIdx.x, ty = threadIdx.y;
  for (int i = ty; i < 32; i += 8)
    tile[i][tx] = Wr[(size_t)(k0 + i) * FDIM + n0 + tx];
  __syncthreads();
  for (int i = ty; i < 32; i += 8)
    Wtr[(size_t)(n0 + i) * K + k0 + tx] = (__bf16)tile[tx][i];
}

// ---- bf16 MFMA GEMM, reg-staged: C[M,512] bf16 = A[M,K] * BT[512,K]^T ----
__global__ __launch_bounds__(256) void k_gemm(const __bf16* __restrict__ A,
                                              const __bf16* __restrict__ BT,
                                              __bf16* __restrict__ C, int M, int K) {
  __shared__ alignas(16) __bf16 lA[128 * 32];
  __shared__ alignas(16) __bf16 lB[128 * 32];
  int t = threadIdx.x, l = t & 63, w = t >> 6;
  int m0 = blockIdx.x * 128, n0 = blockIdx.y * 128;
  int wm = (w >> 1) * 64, wn = (w & 1) * 64;
  f4 acc[4][4] = {};

  for (int k0 = 0; k0 < K; k0 += 32) {
    __syncthreads();
#pragma unroll
    for (int u = 0; u < 2; u++) {
      int q = t + u * 256;          // 0..511
      int row = q >> 2, c = q & 3;  // 4 x 16B chunks per 32-bf16 row
      int ra = m0 + row; if (ra >= M) ra = M - 1;
      bf16x8 va = *(const bf16x8*)(A + (size_t)ra * K + k0 + c * 8);
      *(bf16x8*)(lA + row * 32 + c * 8) = va;
      bf16x8 vb = *(const bf16x8*)(BT + (size_t)(n0 + row) * K + k0 + c * 8);
      *(bf16x8*)(lB + row * 32 + c * 8) = vb;
    }
    __syncthreads();
    bf16x8 a[4], b[4];
#pragma unroll
    for (int i = 0; i < 4; i++) {
      a[i] = *(const bf16x8*)(lA + (wm + i * 16 + (l & 15)) * 32 + (l >> 4) * 8);
      b[i] = *(const bf16x8*)(lB + (wn + i * 16 + (l & 15)) * 32 + (l >> 4) * 8);
    }
#pragma unroll
    for (int i = 0; i < 4; i++)
#pragma unroll
      for (int j = 0; j < 4; j++)
        acc[i][j] = __builtin_amdgcn_mfma_f32_16x16x32_bf16(a[i], b[j], acc[i][j], 0, 0, 0);
  }
  int cn = n0 + wn + (l & 15);
  int rbase = m0 + wm + (l >> 4) * 4;
#pragma unroll
  for (int i = 0; i < 4; i++)
#pragma unroll
    for (int j = 0; j < 4; j++)
#pragma unroll
      for (int q = 0; q < 4; q++) {
        int row = rbase + i * 16 + q;
        if (row < M) C[(size_t)row * FDIM + cn + j * 16] = (__bf16)acc[i][j][q];
      }
}

// ---- el/er: [N,8] = sum_o f[n,h,o]*a[h,o] ----
__global__ void k_elr(const __bf16* __restrict__ f, const float* __restrict__ al,
                      const float* __restrict__ ar, float* __restrict__ el,
                      float* __restrict__ er) {
  int t = threadIdx.x;
  int l = t & 63;
  int node = blockIdx.x * 4 + (t >> 6);
  int h = l >> 3;
  int oc = (l & 7) * 8;
  const f4* ap = (const f4*)(al + h * 64 + oc);
  const f4* bp = (const f4*)(ar + h * 64 + oc);
  f4 a0 = ap[0], a1 = ap[1];
  f4 b0 = bp[0], b1 = bp[1];
  bf16x8 fv = *(const bf16x8*)(f + (size_t)node * FDIM + l * 8);
  f4 f0 = {(float)fv[0], (float)fv[1], (float)fv[2], (float)fv[3]};
  f4 f1 = {(float)fv[4], (float)fv[5], (float)fv[6], (float)fv[7]};
  f4 pl = f0 * a0 + f1 * a1;
  f4 pr = f0 * b0 + f1 * b1;
  float sl = pl.x + pl.y + pl.z + pl.w;
  float sr = pr.x + pr.y + pr.z + pr.w;
  sl += __shfl_xor(sl, 1); sl += __shfl_xor(sl, 2); sl += __shfl_xor(sl, 4);
  sr += __shfl_xor(sr, 1); sr += __shfl_xor(sr, 2); sr += __shfl_xor(sr, 4);
  if ((l & 7) == 0) { el[node * 8 + h] = sl; er[node * 8 + h] = sr; }
}

// ---- CSR build ----
__global__ void k_count(const int* __restrict__ dst, int* __restrict__ deg) {
  int e = blockIdx.x * 256 + threadIdx.x;
  int r = blockIdx.y;
  if (e < NEDGE) {
    int d = dst[(size_t)r * NEDGE + e];
    if ((unsigned)d < (unsigned)NNODES) atomicAdd(&deg[r * NNODES + d], 1);
  }
}

__global__ __launch_bounds__(256) void k_scan_a(const int* __restrict__ in, int* __restrict__ out,
                                                int* __restrict__ bsum, int n) {
  __shared__ int wsums[4];
  int t = threadIdx.x, lane = t & 63, w = t >> 6;
  int base = blockIdx.x * 1024 + t * 4;
  int v0 = base + 0 < n ? in[base + 0] : 0;
  int v1 = base + 1 < n ? in[base + 1] : 0;
  int v2 = base + 2 < n ? in[base + 2] : 0;
  int v3 = base + 3 < n ? in[base + 3] : 0;
  int tot = v0 + v1 + v2 + v3;
  int sc = tot;
#pragma unroll
  for (int off = 1; off < 64; off <<= 1) {
    int u = __shfl_up(sc, off);
    if (lane >= off) sc += u;
  }
  if (lane == 63) wsums[w] = sc;
  __syncthreads();
  int add = 0;
#pragma unroll
  for (int i = 0; i < 4; i++)
    if (i < w) add += wsums[i];
  int excl = add + sc - tot;
  if (base + 0 < n) out[base + 0] = excl;
  if (base + 1 < n) out[base + 1] = excl + v0;
  if (base + 2 < n) out[base + 2] = excl + v0 + v1;
  if (base + 3 < n) out[base + 3] = excl + v0 + v1 + v2;
  if (t == 255) bsum[blockIdx.x] = add + sc;
}

__global__ __launch_bounds__(256) void k_scan_b(int* __restrict__ bsum, int nb) {
  __shared__ int wsums[4];
  int t = threadIdx.x, lane = t & 63, w = t >> 6;
  int i0 = t * 2, i1 = t * 2 + 1;
  int v0 = i0 < nb ? bsum[i0] : 0;
  int v1 = i1 < nb ? bsum[i1] : 0;
  int tot = v0 + v1, sc = tot;
#pragma unroll
  for (int off = 1; off < 64; off <<= 1) {
    int u = __shfl_up(sc, off);
    if (lane >= off) sc += u;
  }
  if (lane == 63) wsums[w] = sc;
  __syncthreads();
  int add = 0;
#pragma unroll
  for (int i = 0; i < 4; i++)
    if (i < w) add += wsums[i];
  int excl = add + sc - tot;
  if (i0 < nb) bsum[i0] = excl;
  if (i1 < nb) bsum[i1] = excl + v0;
}

__global__ void k_scan_c(int* __restrict__ out, const int* __restrict__ bsum, int n) {
  int i = blockIdx.x * 256 + threadIdx.x;
  if (i < n) out[i] += bsum[i >> 10];
}

__global__ void k_scatter(const int* __restrict__ src, const int* __restrict__ dst,
                          const int* __restrict__ ptrf, int* __restrict__ cur,
                          int* __restrict__ csrc) {
  int e = blockIdx.x * 256 + threadIdx.x;
  int r = blockIdx.y;
  if (e >= NEDGE) return;
  int d = dst[(size_t)r * NEDGE + e];
  if ((unsigned)d >= (unsigned)NNODES) return;
  int slot = ptrf[r * NNODES + d] + atomicAdd(&cur[r * NNODES + d], 1);
  if ((unsigned)slot < (unsigned)(NREL * NEDGE))  // insurance
    csrc[slot] = src[(size_t)r * NEDGE + e];
}

// ---- fused segment-softmax + weighted aggregate + ELU + accumulate (wave/dst) ----
template <typename TACC>
__global__ void k_agg(const __bf16* __restrict__ f, const float* __restrict__ el,
                      const float* __restrict__ er, const int* __restrict__ ptrf,
                      const int* __restrict__ deg, const int* __restrict__ csrc,
                      TACC* __restrict__ accG) {
  int t = threadIdx.x;
  int l = t & 63;
  int d = blockIdx.x * 4 + (t >> 6);
  int cnt = deg[d];
  if (cnt <= 0) return;
  int start = ptrf[d];
  if (start < 0) start = 0;
  if (start > NREL * NEDGE) start = NREL * NEDGE;
  if (cnt > NREL * NEDGE - start) cnt = NREL * NEDGE - start;
  int h = l >> 3;
  float erh = er[d * 8 + h];
  float a[8] = {0.f, 0.f, 0.f, 0.f, 0.f, 0.f, 0.f, 0.f};
  float den = 0.f;
  for (int j = 0; j < cnt; j++) {
    int s = csrc[start + j];
    if ((unsigned)s >= (unsigned)NNODES) s = 0;  // insurance
    float e = el[s * 8 + h] + erh;
    e = (e > 0.f) ? e : 0.2f * e;
    float ex = __expf(e);
    den += ex;
    bf16x8 fv = *(const bf16x8*)(f + (size_t)s * FDIM + l * 8);
#pragma unroll
    for (int i = 0; i < 8; i++) a[i] += ex * (float)fv[i];
  }
  float inv = 1.f / (den + 1e-9f);
  float rr[8];
#pragma unroll
  for (int i = 0; i < 8; i++) rr[i] = eluf(a[i] * inv);
  if constexpr (sizeof(TACC) == 4) {
    float* ap = (float*)accG + (size_t)d * FDIM + l * 8;
    f4* vp = (f4*)ap;
    f4 c0 = vp[0], c1 = vp[1];
    c0.x += rr[0]; c0.y += rr[1]; c0.z += rr[2]; c0.w += rr[3];
    c1.x += rr[4]; c1.y += rr[5]; c1.z += rr[6]; c1.w += rr[7];
    vp[0] = c0; vp[1] = c1;
  } else {
    __bf16* ap = (__bf16*)accG + (size_t)d * FDIM + l * 8;
    bf16x8 cv = *(bf16x8*)ap;
    bf16x8 o;
#pragma unroll
    for (int i = 0; i < 8; i++) o[i] = (__bf16)((float)cv[i] + rr[i]);
    *(bf16x8*)ap = o;
  }
}

// ---- final mean over heads ----
template <typename TACC>
__global__ void k_mean(const TACC* __restrict__ acc, float* __restrict__ out) {
  int t = blockIdx.x * 256 + threadIdx.x;
  int n = t >> 6, o = t & 63;
  const TACC* ap = acc + (size_t)n * FDIM + o;
  float s = 0.f;
#pragma unroll
  for (int h = 0; h < 8; h++) s += (float)ap[h * 64];
  out[t] = s * 0.125f;
}

// ---- host ----
extern "C" void kernel_launch(void* const* d_in, const int* in_sizes, int n_in,
                              void* d_out, int out_size, void* d_ws, size_t ws_size,
                              hipStream_t stream) {
  const float* x = (const float*)d_in[0];
  const int* srcp = (const int*)d_in[1];
  const int* dstp = (const int*)d_in[2];
  const float* Wl[3]  = {(const float*)d_in[3], (const float*)d_in[6], (const float*)d_in[9]};
  const float* alp[3] = {(const float*)d_in[4], (const float*)d_in[7], (const float*)d_in[10]};
  const float* arl[3] = {(const float*)d_in[5], (const float*)d_in[8], (const float*)d_in[11]};
  float* out = (float*)d_out;
  (void)in_sizes; (void)n_in; (void)out_size;

  auto rup = [](size_t b) { return (b + 255) & ~(size_t)255; };
  size_t sz_hb   = rup((size_t)NNODES * FDIM * 2);
  size_t sz_fbuf = rup((size_t)NNODES * FDIM * 2);
  size_t sz_el   = rup((size_t)NNODES * NH * 4);
  size_t sz_Wt   = rup((size_t)NREL * FDIM * FDIM * 2);
  size_t sz_int  = rup((size_t)NREL * NNODES * 4);
  size_t sz_csrc = rup((size_t)NREL * NEDGE * 4);
  size_t fixed = sz_hb + sz_fbuf + 2 * sz_el + sz_Wt + 3 * sz_int + sz_csrc + rup(4096);
  size_t need_f32  = fixed + (size_t)NNODES * FDIM * 4;  // ~426 MB
  size_t need_bf16 = fixed + (size_t)NNODES * FDIM * 2;  // ~324 MB
  bool acc_f32;
  if (ws_size >= need_f32) acc_f32 = true;
  else if (ws_size >= need_bf16) acc_f32 = false;
  else return;  // clean diagnostic: zeros out -> absmax == ref absmax, no crash

  char* ws = (char*)d_ws;
  size_t off = 0;
  auto alloc = [&](size_t bytes) -> void* { void* p = ws + off; off += rup(bytes); return p; };
  __bf16* hb   = (__bf16*)alloc((size_t)NNODES * FDIM * 2);
  __bf16* fbuf = (__bf16*)alloc((size_t)NNODES * FDIM * 2);
  float* el    = (float*)alloc((size_t)NNODES * NH * 4);
  float* er    = (float*)alloc((size_t)NNODES * NH * 4);
  __bf16* Wt   = (__bf16*)alloc((size_t)NREL * FDIM * FDIM * 2);
  int* deg  = (int*)alloc((size_t)NREL * NNODES * 4);
  int* ptrf = (int*)alloc((size_t)NREL * NNODES * 4);
  int* cur  = (int*)alloc((size_t)NREL * NNODES * 4);
  int* csrc = (int*)alloc((size_t)NREL * NEDGE * 4);
  int* bsum = (int*)alloc(4096);
  void* accG = alloc((size_t)NNODES * FDIM * (acc_f32 ? 4 : 2));
  size_t accBytes = (size_t)NNODES * FDIM * (acc_f32 ? 4 : 2);

  // ---- CSR by dst ----
  hipMemsetAsync(deg, 0, (size_t)NREL * NNODES * 4, stream);
  hipMemsetAsync(cur, 0, (size_t)NREL * NNODES * 4, stream);
  k_count<<<dim3((NEDGE + 255) / 256, NREL), 256, 0, stream>>>(dstp, deg);
  int ntot = NREL * NNODES;
  int nb1 = (ntot + 1023) / 1024;
  k_scan_a<<<nb1, 256, 0, stream>>>(deg, ptrf, bsum, ntot);
  k_scan_b<<<1, 256, 0, stream>>>(bsum, nb1);
  k_scan_c<<<(ntot + 255) / 256, 256, 0, stream>>>(ptrf, bsum, ntot);
  k_scatter<<<dim3((NEDGE + 255) / 256, NREL), 256, 0, stream>>>(srcp, dstp, ptrf, cur, csrc);

  // ---- 3 layers ----
  for (int L = 0; L < 3; L++) {
    int K = (L == 0) ? 256 : FDIM;
    // layer input -> hb (bf16), decoupled from accG
    if (L == 0)
      k_conv<<<(NNODES * 256) / 1024, 256, 0, stream>>>(x, hb);
    else if (acc_f32)
      k_conv<<<(NNODES * 512) / 1024, 256, 0, stream>>>((const float*)accG, hb);
    else
      k_copyb<<<(NNODES * 512) / 2048, 256, 0, stream>>>((const __bf16*)accG, hb);
    k_transW<<<dim3(K / 32, 16, NREL), dim3(32, 8), 0, stream>>>(Wl[L], Wt, K);
    hipMemsetAsync(accG, 0, accBytes, stream);
    for (int r = 0; r < NREL; r++) {
      k_gemm<<<dim3((NNODES + 127) / 128, 4), 256, 0, stream>>>(
          hb, Wt + (size_t)r * FDIM * K, fbuf, NNODES, K);
      k_elr<<<NNODES / 4, 256, 0, stream>>>(fbuf, alp[L] + r * 512, arl[L] + r * 512, el, er);
      if (acc_f32)
        k_agg<float><<<NNODES / 4, 256, 0, stream>>>(fbuf, el, er, ptrf + r * NNODES,
                                                     deg + r * NNODES, csrc, (float*)accG);
      else
        k_agg<__bf16><<<NNODES / 4, 256, 0, stream>>>(fbuf, el, er, ptrf + r * NNODES,
                                                      deg + r * NNODES, csrc, (__bf16*)accG);
    }
  }
  if (acc_f32) k_mean<float><<<(NNODES * 64) / 256, 256, 0, stream>>>((const float*)accG, out);
  else         k_mean<__bf16><<<(NNODES * 64) / 256, 256, 0, stream>>>((const __bf16*)accG, out);
}

// Round 4
// 2360.428 us; speedup vs baseline: 1.0201x; 1.0201x over previous
//
#include <hip/hip_runtime.h>
#include <hip/hip_bf16.h>
#include <math.h>

#define NNODES 100000
#define NREL 4
#define NEDGE 200000
#define NH 8
#define FDIM 512
#define NMB 782              // ceil(100000/128)
#define GEMM_GRID (NMB * 4)  // 3128, divisible by 8
#define GEMM_CPX (GEMM_GRID / 8)

typedef float f4 __attribute__((ext_vector_type(4)));
typedef __bf16 bf16x8 __attribute__((ext_vector_type(8)));
typedef __bf16 bf16x4 __attribute__((ext_vector_type(4)));

__device__ __forceinline__ float eluf(float v) { return v > 0.f ? v : expm1f(v); }
__device__ __forceinline__ void gload16(const __bf16* g, __bf16* l) {
  __builtin_amdgcn_global_load_lds((const __attribute__((address_space(1))) void*)g,
                                   (__attribute__((address_space(3))) void*)l, 16, 0, 0);
}

// ---- f32 -> bf16 convert (count multiple of 1024) ----
__global__ void k_conv(const float* __restrict__ in, __bf16* __restrict__ outp) {
  int i = (blockIdx.x * 256 + threadIdx.x) * 4;
  f4 v = *(const f4*)(in + i);
  bf16x4 o = {(__bf16)v.x, (__bf16)v.y, (__bf16)v.z, (__bf16)v.w};
  *(bf16x4*)(outp + i) = o;
}
__global__ void k_copyb(const __bf16* __restrict__ in, __bf16* __restrict__ outp) {
  int i = (blockIdx.x * 256 + threadIdx.x) * 8;
  *(bf16x8*)(outp + i) = *(const bf16x8*)(in + i);
}

// ---- W [R,K,512] f32 -> Wt [R,512,K] bf16 ----
__global__ void k_transW(const float* __restrict__ W, __bf16* __restrict__ Wt, int K) {
  __shared__ float tile[32][33];
  int r = blockIdx.z;
  const float* Wr = W + (size_t)r * K * FDIM;
  __bf16* Wtr = Wt + (size_t)r * FDIM * K;
  int k0 = blockIdx.x * 32, n0 = blockIdx.y * 32;
  int tx = threadIdx.x, ty = threadIdx.y;
  for (int i = ty; i < 32; i += 8)
    tile[i][tx] = Wr[(size_t)(k0 + i) * FDIM + n0 + tx];
  __syncthreads();
  for (int i = ty; i < 32; i += 8)
    Wtr[(size_t)(n0 + i) * K + k0 + tx] = (__bf16)tile[tx][i];
}

// ---- bf16 MFMA GEMM (m97 structure: global_load_lds + XCD-chunked swizzle)
//      C[M,512] bf16 = A[M,K] * BT[512,K]^T, fused el/er epilogue ----
__global__ __launch_bounds__(256) void k_gemm(const __bf16* __restrict__ A,
                                              const __bf16* __restrict__ BT,
                                              __bf16* __restrict__ C,
                                              const float* __restrict__ al,
                                              const float* __restrict__ ar,
                                              float* __restrict__ el,
                                              float* __restrict__ er, int M, int K) {
  __shared__ alignas(16) __bf16 lA[128 * 32];
  __shared__ alignas(16) __bf16 lB[128 * 32];
  int t = threadIdx.x, l = t & 63, w = t >> 6;
  // XCD-chunked swizzle: 4 consecutive swz (same A-tile) land on one XCD
  int bid = blockIdx.x;
  int swz = (bid & 7) * GEMM_CPX + (bid >> 3);
  int m0 = (swz >> 2) * 128, n0 = (swz & 3) * 128;
  int wm = (w >> 1) * 64, wn = (w & 1) * 64;
  f4 acc[4][4] = {};
  int r0 = t >> 2, c0 = t & 3;  // staging: thread t -> row r0 (0..63), 16B chunk c0
  int ra = m0 + r0;      if (ra >= M) ra = M - 1;  // clamp: all addresses in-bounds
  int rb = m0 + r0 + 64; if (rb >= M) rb = M - 1;

  for (int k0 = 0; k0 < K; k0 += 32) {
    __syncthreads();
    gload16(A + (size_t)ra * K + k0 + c0 * 8, lA + t * 8);
    gload16(A + (size_t)rb * K + k0 + c0 * 8, lA + (t + 256) * 8);
    gload16(BT + (size_t)(n0 + r0) * K + k0 + c0 * 8, lB + t * 8);
    gload16(BT + (size_t)(n0 + r0 + 64) * K + k0 + c0 * 8, lB + (t + 256) * 8);
    __syncthreads();  // compiler drains vmcnt before barrier -> LDS ready
    bf16x8 a[4], b[4];
#pragma unroll
    for (int i = 0; i < 4; i++) {
      a[i] = *(const bf16x8*)(lA + (wm + i * 16 + (l & 15)) * 32 + (l >> 4) * 8);
      b[i] = *(const bf16x8*)(lB + (wn + i * 16 + (l & 15)) * 32 + (l >> 4) * 8);
    }
#pragma unroll
    for (int i = 0; i < 4; i++)
#pragma unroll
      for (int j = 0; j < 4; j++)
        acc[i][j] = __builtin_amdgcn_mfma_f32_16x16x32_bf16(a[i], b[j], acc[i][j], 0, 0, 0);
  }

  // ---- C write (bf16) ----
  int cn = n0 + wn + (l & 15);
  int rbase = m0 + wm + (l >> 4) * 4;
#pragma unroll
  for (int i = 0; i < 4; i++)
#pragma unroll
    for (int j = 0; j < 4; j++)
#pragma unroll
      for (int q = 0; q < 4; q++) {
        int row = rbase + i * 16 + q;
        if (row < M) C[(size_t)row * FDIM + cn + j * 16] = (__bf16)acc[i][j][q];
      }

  // ---- fused el/er: wave's 64-col slice == one head h; reduce over 16-lane col group ----
  int h = (n0 + wn) >> 6;
  float av[4], bv[4];
#pragma unroll
  for (int j = 0; j < 4; j++) {
    av[j] = al[h * 64 + j * 16 + (l & 15)];
    bv[j] = ar[h * 64 + j * 16 + (l & 15)];
  }
#pragma unroll
  for (int i = 0; i < 4; i++)
#pragma unroll
    for (int q = 0; q < 4; q++) {
      float se = acc[i][0][q] * av[0] + acc[i][1][q] * av[1] +
                 acc[i][2][q] * av[2] + acc[i][3][q] * av[3];
      float sr = acc[i][0][q] * bv[0] + acc[i][1][q] * bv[1] +
                 acc[i][2][q] * bv[2] + acc[i][3][q] * bv[3];
      se += __shfl_xor(se, 1); se += __shfl_xor(se, 2);
      se += __shfl_xor(se, 4); se += __shfl_xor(se, 8);
      sr += __shfl_xor(sr, 1); sr += __shfl_xor(sr, 2);
      sr += __shfl_xor(sr, 4); sr += __shfl_xor(sr, 8);
      if ((l & 15) == 0) {
        int row = rbase + i * 16 + q;
        if (row < M) { el[row * 8 + h] = se; er[row * 8 + h] = sr; }
      }
    }
}

// ---- CSR build ----
__global__ void k_count(const int* __restrict__ dst, int* __restrict__ deg) {
  int e = blockIdx.x * 256 + threadIdx.x;
  int r = blockIdx.y;
  if (e < NEDGE) {
    int d = dst[(size_t)r * NEDGE + e];
    if ((unsigned)d < (unsigned)NNODES) atomicAdd(&deg[r * NNODES + d], 1);
  }
}

__global__ __launch_bounds__(256) void k_scan_a(const int* __restrict__ in, int* __restrict__ out,
                                                int* __restrict__ bsum, int n) {
  __shared__ int wsums[4];
  int t = threadIdx.x, lane = t & 63, w = t >> 6;
  int base = blockIdx.x * 1024 + t * 4;
  int v0 = base + 0 < n ? in[base + 0] : 0;
  int v1 = base + 1 < n ? in[base + 1] : 0;
  int v2 = base + 2 < n ? in[base + 2] : 0;
  int v3 = base + 3 < n ? in[base + 3] : 0;
  int tot = v0 + v1 + v2 + v3;
  int sc = tot;
#pragma unroll
  for (int off = 1; off < 64; off <<= 1) {
    int u = __shfl_up(sc, off);
    if (lane >= off) sc += u;
  }
  if (lane == 63) wsums[w] = sc;
  __syncthreads();
  int add = 0;
#pragma unroll
  for (int i = 0; i < 4; i++)
    if (i < w) add += wsums[i];
  int excl = add + sc - tot;
  if (base + 0 < n) out[base + 0] = excl;
  if (base + 1 < n) out[base + 1] = excl + v0;
  if (base + 2 < n) out[base + 2] = excl + v0 + v1;
  if (base + 3 < n) out[base + 3] = excl + v0 + v1 + v2;
  if (t == 255) bsum[blockIdx.x] = add + sc;
}

__global__ __launch_bounds__(256) void k_scan_b(int* __restrict__ bsum, int nb) {
  __shared__ int wsums[4];
  int t = threadIdx.x, lane = t & 63, w = t >> 6;
  int i0 = t * 2, i1 = t * 2 + 1;
  int v0 = i0 < nb ? bsum[i0] : 0;
  int v1 = i1 < nb ? bsum[i1] : 0;
  int tot = v0 + v1, sc = tot;
#pragma unroll
  for (int off = 1; off < 64; off <<= 1) {
    int u = __shfl_up(sc, off);
    if (lane >= off) sc += u;
  }
  if (lane == 63) wsums[w] = sc;
  __syncthreads();
  int add = 0;
#pragma unroll
  for (int i = 0; i < 4; i++)
    if (i < w) add += wsums[i];
  int excl = add + sc - tot;
  if (i0 < nb) bsum[i0] = excl;
  if (i1 < nb) bsum[i1] = excl + v0;
}

__global__ void k_scan_c(int* __restrict__ out, const int* __restrict__ bsum, int n) {
  int i = blockIdx.x * 256 + threadIdx.x;
  if (i < n) out[i] += bsum[i >> 10];
}

__global__ void k_scatter(const int* __restrict__ src, const int* __restrict__ dst,
                          const int* __restrict__ ptrf, int* __restrict__ cur,
                          int* __restrict__ csrc) {
  int e = blockIdx.x * 256 + threadIdx.x;
  int r = blockIdx.y;
  if (e >= NEDGE) return;
  int d = dst[(size_t)r * NEDGE + e];
  if ((unsigned)d >= (unsigned)NNODES) return;
  int slot = ptrf[r * NNODES + d] + atomicAdd(&cur[r * NNODES + d], 1);
  if ((unsigned)slot < (unsigned)(NREL * NEDGE))
    csrc[slot] = src[(size_t)r * NEDGE + e];
}

// ---- fused segment-softmax + weighted aggregate + ELU + accumulate (wave/dst) ----
template <typename TACC>
__global__ void k_agg(const __bf16* __restrict__ f, const float* __restrict__ el,
                      const float* __restrict__ er, const int* __restrict__ ptrf,
                      const int* __restrict__ deg, const int* __restrict__ csrc,
                      TACC* __restrict__ accG) {
  int t = threadIdx.x;
  int l = t & 63;
  int d = blockIdx.x * 4 + (t >> 6);
  int cnt = deg[d];
  if (cnt <= 0) return;
  int start = ptrf[d];
  if (start < 0) start = 0;
  if (start > NREL * NEDGE) start = NREL * NEDGE;
  if (cnt > NREL * NEDGE - start) cnt = NREL * NEDGE - start;
  int h = l >> 3;
  float erh = er[d * 8 + h];
  float a[8] = {0.f, 0.f, 0.f, 0.f, 0.f, 0.f, 0.f, 0.f};
  float den = 0.f;
  for (int j = 0; j < cnt; j++) {
    int s = csrc[start + j];
    if ((unsigned)s >= (unsigned)NNODES) s = 0;
    float e = el[s * 8 + h] + erh;
    e = (e > 0.f) ? e : 0.2f * e;
    float ex = __expf(e);
    den += ex;
    bf16x8 fv = *(const bf16x8*)(f + (size_t)s * FDIM + l * 8);
#pragma unroll
    for (int i = 0; i < 8; i++) a[i] += ex * (float)fv[i];
  }
  float inv = 1.f / (den + 1e-9f);
  float rr[8];
#pragma unroll
  for (int i = 0; i < 8; i++) rr[i] = eluf(a[i] * inv);
  if constexpr (sizeof(TACC) == 4) {
    float* ap = (float*)accG + (size_t)d * FDIM + l * 8;
    f4* vp = (f4*)ap;
    f4 c0 = vp[0], c1 = vp[1];
    c0.x += rr[0]; c0.y += rr[1]; c0.z += rr[2]; c0.w += rr[3];
    c1.x += rr[4]; c1.y += rr[5]; c1.z += rr[6]; c1.w += rr[7];
    vp[0] = c0; vp[1] = c1;
  } else {
    __bf16* ap = (__bf16*)accG + (size_t)d * FDIM + l * 8;
    bf16x8 cv = *(bf16x8*)ap;
    bf16x8 o;
#pragma unroll
    for (int i = 0; i < 8; i++) o[i] = (__bf16)((float)cv[i] + rr[i]);
    *(bf16x8*)ap = o;
  }
}

// ---- final mean over heads ----
template <typename TACC>
__global__ void k_mean(const TACC* __restrict__ acc, float* __restrict__ out) {
  int t = blockIdx.x * 256 + threadIdx.x;
  int n = t >> 6, o = t & 63;
  const TACC* ap = acc + (size_t)n * FDIM + o;
  float s = 0.f;
#pragma unroll
  for (int h = 0; h < 8; h++) s += (float)ap[h * 64];
  out[t] = s * 0.125f;
}

// ---- host ----
extern "C" void kernel_launch(void* const* d_in, const int* in_sizes, int n_in,
                              void* d_out, int out_size, void* d_ws, size_t ws_size,
                              hipStream_t stream) {
  const float* x = (const float*)d_in[0];
  const int* srcp = (const int*)d_in[1];
  const int* dstp = (const int*)d_in[2];
  const float* Wl[3]  = {(const float*)d_in[3], (const float*)d_in[6], (const float*)d_in[9]};
  const float* alp[3] = {(const float*)d_in[4], (const float*)d_in[7], (const float*)d_in[10]};
  const float* arl[3] = {(const float*)d_in[5], (const float*)d_in[8], (const float*)d_in[11]};
  float* out = (float*)d_out;
  (void)in_sizes; (void)n_in; (void)out_size;

  auto rup = [](size_t b) { return (b + 255) & ~(size_t)255; };
  size_t sz_hb   = rup((size_t)NNODES * FDIM * 2);
  size_t sz_fbuf = rup((size_t)NNODES * FDIM * 2);
  size_t sz_el   = rup((size_t)NNODES * NH * 4);
  size_t sz_Wt   = rup((size_t)NREL * FDIM * FDIM * 2);
  size_t sz_int  = rup((size_t)NREL * NNODES * 4);
  size_t sz_csrc = rup((size_t)NREL * NEDGE * 4);
  size_t fixed = sz_hb + sz_fbuf + 2 * sz_el + sz_Wt + 3 * sz_int + sz_csrc + rup(4096);
  size_t need_f32  = fixed + (size_t)NNODES * FDIM * 4;
  size_t need_bf16 = fixed + (size_t)NNODES * FDIM * 2;
  bool acc_f32;
  if (ws_size >= need_f32) acc_f32 = true;
  else if (ws_size >= need_bf16) acc_f32 = false;
  else return;

  char* ws = (char*)d_ws;
  size_t off = 0;
  auto alloc = [&](size_t bytes) -> void* { void* p = ws + off; off += rup(bytes); return p; };
  __bf16* hb   = (__bf16*)alloc((size_t)NNODES * FDIM * 2);
  __bf16* fbuf = (__bf16*)alloc((size_t)NNODES * FDIM * 2);
  float* el    = (float*)alloc((size_t)NNODES * NH * 4);
  float* er    = (float*)alloc((size_t)NNODES * NH * 4);
  __bf16* Wt   = (__bf16*)alloc((size_t)NREL * FDIM * FDIM * 2);
  int* deg  = (int*)alloc((size_t)NREL * NNODES * 4);
  int* ptrf = (int*)alloc((size_t)NREL * NNODES * 4);
  int* cur  = (int*)alloc((size_t)NREL * NNODES * 4);
  int* csrc = (int*)alloc((size_t)NREL * NEDGE * 4);
  int* bsum = (int*)alloc(4096);
  void* accG = alloc((size_t)NNODES * FDIM * (acc_f32 ? 4 : 2));
  size_t accBytes = (size_t)NNODES * FDIM * (acc_f32 ? 4 : 2);

  // ---- CSR by dst ----
  hipMemsetAsync(deg, 0, (size_t)NREL * NNODES * 4, stream);
  hipMemsetAsync(cur, 0, (size_t)NREL * NNODES * 4, stream);
  k_count<<<dim3((NEDGE + 255) / 256, NREL), 256, 0, stream>>>(dstp, deg);
  int ntot = NREL * NNODES;
  int nb1 = (ntot + 1023) / 1024;
  k_scan_a<<<nb1, 256, 0, stream>>>(deg, ptrf, bsum, ntot);
  k_scan_b<<<1, 256, 0, stream>>>(bsum, nb1);
  k_scan_c<<<(ntot + 255) / 256, 256, 0, stream>>>(ptrf, bsum, ntot);
  k_scatter<<<dim3((NEDGE + 255) / 256, NREL), 256, 0, stream>>>(srcp, dstp, ptrf, cur, csrc);

  // ---- 3 layers ----
  for (int L = 0; L < 3; L++) {
    int K = (L == 0) ? 256 : FDIM;
    if (L == 0)
      k_conv<<<(NNODES * 256) / 1024, 256, 0, stream>>>(x, hb);
    else if (acc_f32)
      k_conv<<<(NNODES * 512) / 1024, 256, 0, stream>>>((const float*)accG, hb);
    else
      k_copyb<<<(NNODES * 512) / 2048, 256, 0, stream>>>((const __bf16*)accG, hb);
    k_transW<<<dim3(K / 32, 16, NREL), dim3(32, 8), 0, stream>>>(Wl[L], Wt, K);
    hipMemsetAsync(accG, 0, accBytes, stream);
    for (int r = 0; r < NREL; r++) {
      k_gemm<<<GEMM_GRID, 256, 0, stream>>>(hb, Wt + (size_t)r * FDIM * K, fbuf,
                                            alp[L] + r * 512, arl[L] + r * 512,
                                            el, er, NNODES, K);
      if (acc_f32)
        k_agg<float><<<NNODES / 4, 256, 0, stream>>>(fbuf, el, er, ptrf + r * NNODES,
                                                     deg + r * NNODES, csrc, (float*)accG);
      else
        k_agg<__bf16><<<NNODES / 4, 256, 0, stream>>>(fbuf, el, er, ptrf + r * NNODES,
                                                      deg + r * NNODES, csrc, (__bf16*)accG);
    }
  }
  if (acc_f32) k_mean<float><<<(NNODES * 64) / 256, 256, 0, stream>>>((const float*)accG, out);
  else         k_mean<__bf16><<<(NNODES * 64) / 256, 256, 0, stream>>>((const __bf16*)accG, out);
}

// Round 5
// 2250.630 us; speedup vs baseline: 1.0698x; 1.0488x over previous
//
#include <hip/hip_runtime.h>
#include <hip/hip_bf16.h>
#include <math.h>

#define NNODES 100000
#define NREL 4
#define NEDGE 200000
#define NH 8
#define FDIM 512
#define NMB 782              // ceil(100000/128)
#define GEMM_GRID (NMB * 4)  // 3128, divisible by 8
#define GEMM_CPX (GEMM_GRID / 8)

typedef float f4 __attribute__((ext_vector_type(4)));
typedef __bf16 bf16x8 __attribute__((ext_vector_type(8)));
typedef __bf16 bf16x4 __attribute__((ext_vector_type(4)));

__device__ __forceinline__ float eluf(float v) { return v > 0.f ? v : expm1f(v); }
__device__ __forceinline__ void gload16(const __bf16* g, __bf16* l) {
  __builtin_amdgcn_global_load_lds((const __attribute__((address_space(1))) void*)g,
                                   (__attribute__((address_space(3))) void*)l, 16, 0, 0);
}

// ---- f32 -> bf16 convert (count multiple of 1024) ----
__global__ void k_conv(const float* __restrict__ in, __bf16* __restrict__ outp) {
  int i = (blockIdx.x * 256 + threadIdx.x) * 4;
  f4 v = *(const f4*)(in + i);
  bf16x4 o = {(__bf16)v.x, (__bf16)v.y, (__bf16)v.z, (__bf16)v.w};
  *(bf16x4*)(outp + i) = o;
}
__global__ void k_copyb(const __bf16* __restrict__ in, __bf16* __restrict__ outp) {
  int i = (blockIdx.x * 256 + threadIdx.x) * 8;
  *(bf16x8*)(outp + i) = *(const bf16x8*)(in + i);
}

// ---- W [R,K,512] f32 -> Wt [R,512,K] bf16 ----
__global__ void k_transW(const float* __restrict__ W, __bf16* __restrict__ Wt, int K) {
  __shared__ float tile[32][33];
  int r = blockIdx.z;
  const float* Wr = W + (size_t)r * K * FDIM;
  __bf16* Wtr = Wt + (size_t)r * FDIM * K;
  int k0 = blockIdx.x * 32, n0 = blockIdx.y * 32;
  int tx = threadIdx.x, ty = threadIdx.y;
  for (int i = ty; i < 32; i += 8)
    tile[i][tx] = Wr[(size_t)(k0 + i) * FDIM + n0 + tx];
  __syncthreads();
  for (int i = ty; i < 32; i += 8)
    Wtr[(size_t)(n0 + i) * K + k0 + tx] = (__bf16)tile[tx][i];
}

// ---- bf16 MFMA GEMM: 2-phase double-buffered global_load_lds + XCD swizzle
//      C[M,512] bf16 = A[M,K] * BT[512,K]^T, fused el/er epilogue ----
__global__ __launch_bounds__(256) void k_gemm(const __bf16* __restrict__ A,
                                              const __bf16* __restrict__ BT,
                                              __bf16* __restrict__ C,
                                              const float* __restrict__ al,
                                              const float* __restrict__ ar,
                                              float* __restrict__ el,
                                              float* __restrict__ er, int M, int K) {
  __shared__ alignas(16) __bf16 lA[2][128 * 32];
  __shared__ alignas(16) __bf16 lB[2][128 * 32];
  int t = threadIdx.x, l = t & 63, w = t >> 6;
  int bid = blockIdx.x;
  int swz = (bid & 7) * GEMM_CPX + (bid >> 3);
  int m0 = (swz >> 2) * 128, n0 = (swz & 3) * 128;
  int wm = (w >> 1) * 64, wn = (w & 1) * 64;
  f4 acc[4][4] = {};
  int r0 = t >> 2, c0 = t & 3;  // staging: thread t -> row r0 (0..63), 16B chunk c0
  int ra = m0 + r0;      if (ra >= M) ra = M - 1;
  int rb = m0 + r0 + 64; if (rb >= M) rb = M - 1;
  const __bf16* gA0 = A + (size_t)ra * K + c0 * 8;
  const __bf16* gA1 = A + (size_t)rb * K + c0 * 8;
  const __bf16* gB0 = BT + (size_t)(n0 + r0) * K + c0 * 8;
  const __bf16* gB1 = BT + (size_t)(n0 + r0 + 64) * K + c0 * 8;

#define STAGE(buf, k0)                          \
  do {                                          \
    gload16(gA0 + (k0), &lA[buf][t * 8]);       \
    gload16(gA1 + (k0), &lA[buf][(t + 256) * 8]); \
    gload16(gB0 + (k0), &lB[buf][t * 8]);       \
    gload16(gB1 + (k0), &lB[buf][(t + 256) * 8]); \
  } while (0)

  STAGE(0, 0);
  __syncthreads();  // drain vmcnt: buf0 ready
  int nt = K >> 5;
  int cur = 0;
  for (int kt = 0; kt < nt; kt++) {
    if (kt + 1 < nt) STAGE(cur ^ 1, (kt + 1) * 32);  // prefetch flies under MFMA
    bf16x8 a[4], b[4];
#pragma unroll
    for (int i = 0; i < 4; i++) {
      a[i] = *(const bf16x8*)(&lA[cur][(wm + i * 16 + (l & 15)) * 32 + (l >> 4) * 8]);
      b[i] = *(const bf16x8*)(&lB[cur][(wn + i * 16 + (l & 15)) * 32 + (l >> 4) * 8]);
    }
#pragma unroll
    for (int i = 0; i < 4; i++)
#pragma unroll
      for (int j = 0; j < 4; j++)
        acc[i][j] = __builtin_amdgcn_mfma_f32_16x16x32_bf16(a[i], b[j], acc[i][j], 0, 0, 0);
    __syncthreads();  // drain: next buffer landed; readers done with cur
    cur ^= 1;
  }
#undef STAGE

  // ---- C write (bf16) ----
  int cn = n0 + wn + (l & 15);
  int rbase = m0 + wm + (l >> 4) * 4;
#pragma unroll
  for (int i = 0; i < 4; i++)
#pragma unroll
    for (int j = 0; j < 4; j++)
#pragma unroll
      for (int q = 0; q < 4; q++) {
        int row = rbase + i * 16 + q;
        if (row < M) C[(size_t)row * FDIM + cn + j * 16] = (__bf16)acc[i][j][q];
      }

  // ---- fused el/er: wave's 64-col slice == one head h ----
  int h = (n0 + wn) >> 6;
  float av[4], bv[4];
#pragma unroll
  for (int j = 0; j < 4; j++) {
    av[j] = al[h * 64 + j * 16 + (l & 15)];
    bv[j] = ar[h * 64 + j * 16 + (l & 15)];
  }
#pragma unroll
  for (int i = 0; i < 4; i++)
#pragma unroll
    for (int q = 0; q < 4; q++) {
      float se = acc[i][0][q] * av[0] + acc[i][1][q] * av[1] +
                 acc[i][2][q] * av[2] + acc[i][3][q] * av[3];
      float sr = acc[i][0][q] * bv[0] + acc[i][1][q] * bv[1] +
                 acc[i][2][q] * bv[2] + acc[i][3][q] * bv[3];
      se += __shfl_xor(se, 1); se += __shfl_xor(se, 2);
      se += __shfl_xor(se, 4); se += __shfl_xor(se, 8);
      sr += __shfl_xor(sr, 1); sr += __shfl_xor(sr, 2);
      sr += __shfl_xor(sr, 4); sr += __shfl_xor(sr, 8);
      if ((l & 15) == 0) {
        int row = rbase + i * 16 + q;
        if (row < M) { el[row * 8 + h] = se; er[row * 8 + h] = sr; }
      }
    }
}

// ---- CSR build ----
__global__ void k_count(const int* __restrict__ dst, int* __restrict__ deg) {
  int e = blockIdx.x * 256 + threadIdx.x;
  int r = blockIdx.y;
  if (e < NEDGE) {
    int d = dst[(size_t)r * NEDGE + e];
    if ((unsigned)d < (unsigned)NNODES) atomicAdd(&deg[r * NNODES + d], 1);
  }
}

__global__ __launch_bounds__(256) void k_scan_a(const int* __restrict__ in, int* __restrict__ out,
                                                int* __restrict__ bsum, int n) {
  __shared__ int wsums[4];
  int t = threadIdx.x, lane = t & 63, w = t >> 6;
  int base = blockIdx.x * 1024 + t * 4;
  int v0 = base + 0 < n ? in[base + 0] : 0;
  int v1 = base + 1 < n ? in[base + 1] : 0;
  int v2 = base + 2 < n ? in[base + 2] : 0;
  int v3 = base + 3 < n ? in[base + 3] : 0;
  int tot = v0 + v1 + v2 + v3;
  int sc = tot;
#pragma unroll
  for (int off = 1; off < 64; off <<= 1) {
    int u = __shfl_up(sc, off);
    if (lane >= off) sc += u;
  }
  if (lane == 63) wsums[w] = sc;
  __syncthreads();
  int add = 0;
#pragma unroll
  for (int i = 0; i < 4; i++)
    if (i < w) add += wsums[i];
  int excl = add + sc - tot;
  if (base + 0 < n) out[base + 0] = excl;
  if (base + 1 < n) out[base + 1] = excl + v0;
  if (base + 2 < n) out[base + 2] = excl + v0 + v1;
  if (base + 3 < n) out[base + 3] = excl + v0 + v1 + v2;
  if (t == 255) bsum[blockIdx.x] = add + sc;
}

__global__ __launch_bounds__(256) void k_scan_b(int* __restrict__ bsum, int nb) {
  __shared__ int wsums[4];
  int t = threadIdx.x, lane = t & 63, w = t >> 6;
  int i0 = t * 2, i1 = t * 2 + 1;
  int v0 = i0 < nb ? bsum[i0] : 0;
  int v1 = i1 < nb ? bsum[i1] : 0;
  int tot = v0 + v1, sc = tot;
#pragma unroll
  for (int off = 1; off < 64; off <<= 1) {
    int u = __shfl_up(sc, off);
    if (lane >= off) sc += u;
  }
  if (lane == 63) wsums[w] = sc;
  __syncthreads();
  int add = 0;
#pragma unroll
  for (int i = 0; i < 4; i++)
    if (i < w) add += wsums[i];
  int excl = add + sc - tot;
  if (i0 < nb) bsum[i0] = excl;
  if (i1 < nb) bsum[i1] = excl + v0;
}

__global__ void k_scan_c(int* __restrict__ out, const int* __restrict__ bsum, int n) {
  int i = blockIdx.x * 256 + threadIdx.x;
  if (i < n) out[i] += bsum[i >> 10];
}

__global__ void k_scatter(const int* __restrict__ src, const int* __restrict__ dst,
                          const int* __restrict__ ptrf, int* __restrict__ cur,
                          int* __restrict__ csrc) {
  int e = blockIdx.x * 256 + threadIdx.x;
  int r = blockIdx.y;
  if (e >= NEDGE) return;
  int d = dst[(size_t)r * NEDGE + e];
  if ((unsigned)d >= (unsigned)NNODES) return;
  int slot = ptrf[r * NNODES + d] + atomicAdd(&cur[r * NNODES + d], 1);
  if ((unsigned)slot < (unsigned)(NREL * NEDGE))
    csrc[slot] = src[(size_t)r * NEDGE + e];
}

// ---- fused segment-softmax + weighted aggregate + ELU + accumulate (wave/dst), bf16 acc ----
__global__ void k_agg(const __bf16* __restrict__ f, const float* __restrict__ el,
                      const float* __restrict__ er, const int* __restrict__ ptrf,
                      const int* __restrict__ deg, const int* __restrict__ csrc,
                      __bf16* __restrict__ accG) {
  int t = threadIdx.x;
  int l = t & 63;
  int d = blockIdx.x * 4 + (t >> 6);
  int cnt = deg[d];
  if (cnt <= 0) return;
  int start = ptrf[d];
  if (start < 0) start = 0;
  if (start > NREL * NEDGE) start = NREL * NEDGE;
  if (cnt > NREL * NEDGE - start) cnt = NREL * NEDGE - start;
  int h = l >> 3;
  float erh = er[d * 8 + h];
  float a[8] = {0.f, 0.f, 0.f, 0.f, 0.f, 0.f, 0.f, 0.f};
  float den = 0.f;
  for (int j = 0; j < cnt; j++) {
    int s = csrc[start + j];
    if ((unsigned)s >= (unsigned)NNODES) s = 0;
    float e = el[s * 8 + h] + erh;
    e = (e > 0.f) ? e : 0.2f * e;
    float ex = __expf(e);
    den += ex;
    bf16x8 fv = *(const bf16x8*)(f + (size_t)s * FDIM + l * 8);
#pragma unroll
    for (int i = 0; i < 8; i++) a[i] += ex * (float)fv[i];
  }
  float inv = 1.f / (den + 1e-9f);
  __bf16* ap = accG + (size_t)d * FDIM + l * 8;
  bf16x8 cv = *(bf16x8*)ap;
  bf16x8 o;
#pragma unroll
  for (int i = 0; i < 8; i++) o[i] = (__bf16)((float)cv[i] + eluf(a[i] * inv));
  *(bf16x8*)ap = o;
}

// ---- final mean over heads ----
__global__ void k_mean(const __bf16* __restrict__ acc, float* __restrict__ out) {
  int t = blockIdx.x * 256 + threadIdx.x;
  int n = t >> 6, o = t & 63;
  const __bf16* ap = acc + (size_t)n * FDIM + o;
  float s = 0.f;
#pragma unroll
  for (int h = 0; h < 8; h++) s += (float)ap[h * 64];
  out[t] = s * 0.125f;
}

// ---- host ----
extern "C" void kernel_launch(void* const* d_in, const int* in_sizes, int n_in,
                              void* d_out, int out_size, void* d_ws, size_t ws_size,
                              hipStream_t stream) {
  const float* x = (const float*)d_in[0];
  const int* srcp = (const int*)d_in[1];
  const int* dstp = (const int*)d_in[2];
  const float* Wl[3]  = {(const float*)d_in[3], (const float*)d_in[6], (const float*)d_in[9]};
  const float* alp[3] = {(const float*)d_in[4], (const float*)d_in[7], (const float*)d_in[10]};
  const float* arl[3] = {(const float*)d_in[5], (const float*)d_in[8], (const float*)d_in[11]};
  float* out = (float*)d_out;
  (void)in_sizes; (void)n_in; (void)out_size;

  auto rup = [](size_t b) { return (b + 255) & ~(size_t)255; };
  size_t need = rup((size_t)NNODES * FDIM * 2) * 3 +      // hb, fbuf, accG (bf16)
                rup((size_t)NNODES * NH * 4) * 2 +        // el, er
                rup((size_t)NREL * FDIM * FDIM * 2) +     // Wt
                rup((size_t)NREL * NNODES * 4) * 3 +      // deg, ptrf, cur
                rup((size_t)NREL * NEDGE * 4) + rup(4096);
  if (ws_size < need) return;  // diagnostic: zeros out, no crash

  char* ws = (char*)d_ws;
  size_t off = 0;
  auto alloc = [&](size_t bytes) -> void* { void* p = ws + off; off += rup(bytes); return p; };
  __bf16* hb   = (__bf16*)alloc((size_t)NNODES * FDIM * 2);
  __bf16* fbuf = (__bf16*)alloc((size_t)NNODES * FDIM * 2);
  __bf16* accG = (__bf16*)alloc((size_t)NNODES * FDIM * 2);
  float* el    = (float*)alloc((size_t)NNODES * NH * 4);
  float* er    = (float*)alloc((size_t)NNODES * NH * 4);
  __bf16* Wt   = (__bf16*)alloc((size_t)NREL * FDIM * FDIM * 2);
  int* deg  = (int*)alloc((size_t)NREL * NNODES * 4);
  int* ptrf = (int*)alloc((size_t)NREL * NNODES * 4);
  int* cur  = (int*)alloc((size_t)NREL * NNODES * 4);
  int* csrc = (int*)alloc((size_t)NREL * NEDGE * 4);
  int* bsum = (int*)alloc(4096);

  // ---- CSR by dst ----
  hipMemsetAsync(deg, 0, (size_t)NREL * NNODES * 4, stream);
  hipMemsetAsync(cur, 0, (size_t)NREL * NNODES * 4, stream);
  k_count<<<dim3((NEDGE + 255) / 256, NREL), 256, 0, stream>>>(dstp, deg);
  int ntot = NREL * NNODES;
  int nb1 = (ntot + 1023) / 1024;
  k_scan_a<<<nb1, 256, 0, stream>>>(deg, ptrf, bsum, ntot);
  k_scan_b<<<1, 256, 0, stream>>>(bsum, nb1);
  k_scan_c<<<(ntot + 255) / 256, 256, 0, stream>>>(ptrf, bsum, ntot);
  k_scatter<<<dim3((NEDGE + 255) / 256, NREL), 256, 0, stream>>>(srcp, dstp, ptrf, cur, csrc);

  // ---- 3 layers ----
  for (int L = 0; L < 3; L++) {
    int K = (L == 0) ? 256 : FDIM;
    if (L == 0)
      k_conv<<<(NNODES * 256) / 1024, 256, 0, stream>>>(x, hb);
    else
      k_copyb<<<(NNODES * 512) / 2048, 256, 0, stream>>>(accG, hb);
    k_transW<<<dim3(K / 32, 16, NREL), dim3(32, 8), 0, stream>>>(Wl[L], Wt, K);
    hipMemsetAsync(accG, 0, (size_t)NNODES * FDIM * 2, stream);
    for (int r = 0; r < NREL; r++) {
      k_gemm<<<GEMM_GRID, 256, 0, stream>>>(hb, Wt + (size_t)r * FDIM * K, fbuf,
                                            alp[L] + r * 512, arl[L] + r * 512,
                                            el, er, NNODES, K);
      k_agg<<<NNODES / 4, 256, 0, stream>>>(fbuf, el, er, ptrf + r * NNODES,
                                            deg + r * NNODES, csrc, accG);
    }
  }
  k_mean<<<(NNODES * 64) / 256, 256, 0, stream>>>(accG, out);
}

// Round 6
// 2222.060 us; speedup vs baseline: 1.0836x; 1.0129x over previous
//
#include <hip/hip_runtime.h>
#include <hip/hip_bf16.h>
#include <math.h>

#define NNODES 100000
#define NREL 4
#define NEDGE 200000
#define NH 8
#define FDIM 512
#define NMB 782  // ceil(100000/128)

typedef float f4 __attribute__((ext_vector_type(4)));
typedef __bf16 bf16x8 __attribute__((ext_vector_type(8)));
typedef __bf16 bf16x4 __attribute__((ext_vector_type(4)));

__device__ __forceinline__ float eluf(float v) { return v > 0.f ? v : expm1f(v); }
__device__ __forceinline__ void gload16(const __bf16* g, __bf16* l) {
  __builtin_amdgcn_global_load_lds((const __attribute__((address_space(1))) void*)g,
                                   (__attribute__((address_space(3))) void*)l, 16, 0, 0);
}

// ---- f32 -> bf16 convert (count multiple of 1024) ----
__global__ void k_conv(const float* __restrict__ in, __bf16* __restrict__ outp) {
  int i = (blockIdx.x * 256 + threadIdx.x) * 4;
  f4 v = *(const f4*)(in + i);
  bf16x4 o = {(__bf16)v.x, (__bf16)v.y, (__bf16)v.z, (__bf16)v.w};
  *(bf16x4*)(outp + i) = o;
}
__global__ void k_copyb(const __bf16* __restrict__ in, __bf16* __restrict__ outp) {
  int i = (blockIdx.x * 256 + threadIdx.x) * 8;
  *(bf16x8*)(outp + i) = *(const bf16x8*)(in + i);
}

// ---- W [R,K,512] f32 -> Wt [R*512, K] bf16 (transposed) ----
__global__ void k_transW(const float* __restrict__ W, __bf16* __restrict__ Wt, int K) {
  __shared__ float tile[32][33];
  int r = blockIdx.z;
  const float* Wr = W + (size_t)r * K * FDIM;
  __bf16* Wtr = Wt + (size_t)r * FDIM * K;
  int k0 = blockIdx.x * 32, n0 = blockIdx.y * 32;
  int tx = threadIdx.x, ty = threadIdx.y;
  for (int i = ty; i < 32; i += 8)
    tile[i][tx] = Wr[(size_t)(k0 + i) * FDIM + n0 + tx];
  __syncthreads();
  for (int i = ty; i < 32; i += 8)
    Wtr[(size_t)(n0 + i) * K + k0 + tx] = (__bf16)tile[tx][i];
}

// ---- bf16 MFMA GEMM: 3-deep counted-vmcnt pipeline + XCD-chunked swizzle ----
__global__ __launch_bounds__(256) void k_gemm(const __bf16* __restrict__ A,
                                              const __bf16* __restrict__ BT,
                                              __bf16* __restrict__ C,
                                              const float* __restrict__ al,
                                              const float* __restrict__ ar,
                                              float* __restrict__ el,
                                              float* __restrict__ er, int M, int K,
                                              int nb4shift, int cpx) {
  __shared__ alignas(16) __bf16 lA[3][128 * 32];
  __shared__ alignas(16) __bf16 lB[3][128 * 32];
  int t = threadIdx.x, l = t & 63, w = t >> 6;
  int bid = blockIdx.x;
  int swz = (bid & 7) * cpx + (bid >> 3);
  int nb4mask = (1 << nb4shift) - 1;
  int m0 = (swz >> nb4shift) * 128, n0 = (swz & nb4mask) * 128;
  int NDIM = 128 << nb4shift;
  int nh_tot = 2 << nb4shift;
  int wm = (w >> 1) * 64, wn = (w & 1) * 64;
  f4 acc[4][4] = {};
  int r0 = t >> 2, c0 = t & 3;
  int ra = m0 + r0;      if (ra >= M) ra = M - 1;
  int rb = m0 + r0 + 64; if (rb >= M) rb = M - 1;
  const __bf16* gA0 = A + (size_t)ra * K + c0 * 8;
  const __bf16* gA1 = A + (size_t)rb * K + c0 * 8;
  const __bf16* gB0 = BT + (size_t)(n0 + r0) * K + c0 * 8;
  const __bf16* gB1 = BT + (size_t)(n0 + r0 + 64) * K + c0 * 8;

#define STAGE(buf, kk)                              \
  do {                                              \
    gload16(gA0 + (kk), &lA[buf][t * 8]);           \
    gload16(gA1 + (kk), &lA[buf][(t + 256) * 8]);   \
    gload16(gB0 + (kk), &lB[buf][t * 8]);           \
    gload16(gB1 + (kk), &lB[buf][(t + 256) * 8]);   \
  } while (0)

  int nt = K >> 5;  // 8 or 16 (>= 3)
  STAGE(0, 0);
  STAGE(1, 32);
  STAGE(2, 64);
  int cur = 0;
  for (int kt = 0; kt < nt; kt++) {
    int rem = nt - 1 - kt;
    if (rem >= 2)      asm volatile("s_waitcnt vmcnt(8)" ::: "memory");
    else if (rem == 1) asm volatile("s_waitcnt vmcnt(4)" ::: "memory");
    else               asm volatile("s_waitcnt vmcnt(0)" ::: "memory");
    __builtin_amdgcn_s_barrier();  // tile kt landed (all waves)
    bf16x8 a[4], b[4];
#pragma unroll
    for (int i = 0; i < 4; i++) {
      a[i] = *(const bf16x8*)(&lA[cur][(wm + i * 16 + (l & 15)) * 32 + (l >> 4) * 8]);
      b[i] = *(const bf16x8*)(&lB[cur][(wn + i * 16 + (l & 15)) * 32 + (l >> 4) * 8]);
    }
    asm volatile("s_waitcnt lgkmcnt(0)" ::: "memory");
    __builtin_amdgcn_s_barrier();  // all waves done reading buf cur (WAR safe)
    if (kt + 3 < nt) STAGE(cur, (kt + 3) * 32);  // restage flies under MFMA
#pragma unroll
    for (int i = 0; i < 4; i++)
#pragma unroll
      for (int j = 0; j < 4; j++)
        acc[i][j] = __builtin_amdgcn_mfma_f32_16x16x32_bf16(a[i], b[j], acc[i][j], 0, 0, 0);
    cur = (cur == 2) ? 0 : cur + 1;
  }
#undef STAGE

  int cn = n0 + wn + (l & 15);
  int rbase = m0 + wm + (l >> 4) * 4;
#pragma unroll
  for (int i = 0; i < 4; i++)
#pragma unroll
    for (int j = 0; j < 4; j++)
#pragma unroll
      for (int q = 0; q < 4; q++) {
        int row = rbase + i * 16 + q;
        if (row < M) C[(size_t)row * NDIM + cn + j * 16] = (__bf16)acc[i][j][q];
      }

  int h = (n0 + wn) >> 6;
  float av[4], bv[4];
#pragma unroll
  for (int j = 0; j < 4; j++) {
    av[j] = al[h * 64 + j * 16 + (l & 15)];
    bv[j] = ar[h * 64 + j * 16 + (l & 15)];
  }
#pragma unroll
  for (int i = 0; i < 4; i++)
#pragma unroll
    for (int q = 0; q < 4; q++) {
      float se = acc[i][0][q] * av[0] + acc[i][1][q] * av[1] +
                 acc[i][2][q] * av[2] + acc[i][3][q] * av[3];
      float sr = acc[i][0][q] * bv[0] + acc[i][1][q] * bv[1] +
                 acc[i][2][q] * bv[2] + acc[i][3][q] * bv[3];
      se += __shfl_xor(se, 1); se += __shfl_xor(se, 2);
      se += __shfl_xor(se, 4); se += __shfl_xor(se, 8);
      sr += __shfl_xor(sr, 1); sr += __shfl_xor(sr, 2);
      sr += __shfl_xor(sr, 4); sr += __shfl_xor(sr, 8);
      if ((l & 15) == 0) {
        int row = rbase + i * 16 + q;
        if (row < M) { el[row * nh_tot + h] = se; er[row * nh_tot + h] = sr; }
      }
    }
}

// ---- CSR build ----
__global__ void k_count(const int* __restrict__ dst, int* __restrict__ deg) {
  int e = blockIdx.x * 256 + threadIdx.x;
  int r = blockIdx.y;
  if (e < NEDGE) {
    int d = dst[(size_t)r * NEDGE + e];
    if ((unsigned)d < (unsigned)NNODES) atomicAdd(&deg[r * NNODES + d], 1);
  }
}

__global__ __launch_bounds__(256) void k_scan_a(const int* __restrict__ in, int* __restrict__ out,
                                                int* __restrict__ bsum, int n) {
  __shared__ int wsums[4];
  int t = threadIdx.x, lane = t & 63, w = t >> 6;
  int base = blockIdx.x * 1024 + t * 4;
  int v0 = base + 0 < n ? in[base + 0] : 0;
  int v1 = base + 1 < n ? in[base + 1] : 0;
  int v2 = base + 2 < n ? in[base + 2] : 0;
  int v3 = base + 3 < n ? in[base + 3] : 0;
  int tot = v0 + v1 + v2 + v3;
  int sc = tot;
#pragma unroll
  for (int off = 1; off < 64; off <<= 1) {
    int u = __shfl_up(sc, off);
    if (lane >= off) sc += u;
  }
  if (lane == 63) wsums[w] = sc;
  __syncthreads();
  int add = 0;
#pragma unroll
  for (int i = 0; i < 4; i++)
    if (i < w) add += wsums[i];
  int excl = add + sc - tot;
  if (base + 0 < n) out[base + 0] = excl;
  if (base + 1 < n) out[base + 1] = excl + v0;
  if (base + 2 < n) out[base + 2] = excl + v0 + v1;
  if (base + 3 < n) out[base + 3] = excl + v0 + v1 + v2;
  if (t == 255) bsum[blockIdx.x] = add + sc;
}

__global__ __launch_bounds__(256) void k_scan_b(int* __restrict__ bsum, int nb) {
  __shared__ int wsums[4];
  int t = threadIdx.x, lane = t & 63, w = t >> 6;
  int i0 = t * 2, i1 = t * 2 + 1;
  int v0 = i0 < nb ? bsum[i0] : 0;
  int v1 = i1 < nb ? bsum[i1] : 0;
  int tot = v0 + v1, sc = tot;
#pragma unroll
  for (int off = 1; off < 64; off <<= 1) {
    int u = __shfl_up(sc, off);
    if (lane >= off) sc += u;
  }
  if (lane == 63) wsums[w] = sc;
  __syncthreads();
  int add = 0;
#pragma unroll
  for (int i = 0; i < 4; i++)
    if (i < w) add += wsums[i];
  int excl = add + sc - tot;
  if (i0 < nb) bsum[i0] = excl;
  if (i1 < nb) bsum[i1] = excl + v0;
}

__global__ void k_scan_c(int* __restrict__ out, const int* __restrict__ bsum, int n) {
  int i = blockIdx.x * 256 + threadIdx.x;
  if (i < n) out[i] += bsum[i >> 10];
}

__global__ void k_scatter(const int* __restrict__ src, const int* __restrict__ dst,
                          const int* __restrict__ ptrf, int* __restrict__ cur,
                          int* __restrict__ csrc) {
  int e = blockIdx.x * 256 + threadIdx.x;
  int r = blockIdx.y;
  if (e >= NEDGE) return;
  int d = dst[(size_t)r * NEDGE + e];
  if ((unsigned)d >= (unsigned)NNODES) return;
  int slot = ptrf[r * NNODES + d] + atomicAdd(&cur[r * NNODES + d], 1);
  if ((unsigned)slot < (unsigned)(NREL * NEDGE))
    csrc[slot] = src[(size_t)r * NEDGE + e];
}

// ---- fused segment-softmax + aggregate + ELU + accumulate (wave/dst), bf16 acc ----
__global__ void k_agg(const __bf16* __restrict__ f, const float* __restrict__ el,
                      const float* __restrict__ er, const int* __restrict__ ptrf,
                      const int* __restrict__ deg, const int* __restrict__ csrc,
                      __bf16* __restrict__ accG, int fstride, int coff, int estride, int eoff) {
  int t = threadIdx.x;
  int l = t & 63;
  int d = blockIdx.x * 4 + (t >> 6);
  int cnt = deg[d];
  if (cnt <= 0) return;
  int start = ptrf[d];
  if (start < 0) start = 0;
  if (start > NREL * NEDGE) start = NREL * NEDGE;
  if (cnt > NREL * NEDGE - start) cnt = NREL * NEDGE - start;
  int h = l >> 3;
  float erh = er[d * estride + eoff + h];
  float a[8] = {0.f, 0.f, 0.f, 0.f, 0.f, 0.f, 0.f, 0.f};
  float den = 0.f;
  for (int j = 0; j < cnt; j++) {
    int s = csrc[start + j];
    if ((unsigned)s >= (unsigned)NNODES) s = 0;
    float e = el[s * estride + eoff + h] + erh;
    e = (e > 0.f) ? e : 0.2f * e;
    float ex = __expf(e);
    den += ex;
    bf16x8 fv = *(const bf16x8*)(f + (size_t)s * fstride + coff + l * 8);
#pragma unroll
    for (int i = 0; i < 8; i++) a[i] += ex * (float)fv[i];
  }
  float inv = 1.f / (den + 1e-9f);
  __bf16* ap = accG + (size_t)d * FDIM + l * 8;
  bf16x8 cv = *(bf16x8*)ap;
  bf16x8 o;
#pragma unroll
  for (int i = 0; i < 8; i++) o[i] = (__bf16)((float)cv[i] + eluf(a[i] * inv));
  *(bf16x8*)ap = o;
}

// ---- final mean over heads ----
__global__ void k_mean(const __bf16* __restrict__ acc, float* __restrict__ out) {
  int t = blockIdx.x * 256 + threadIdx.x;
  int n = t >> 6, o = t & 63;
  const __bf16* ap = acc + (size_t)n * FDIM + o;
  float s = 0.f;
#pragma unroll
  for (int h = 0; h < 8; h++) s += (float)ap[h * 64];
  out[t] = s * 0.125f;
}

// ---- host ----
extern "C" void kernel_launch(void* const* d_in, const int* in_sizes, int n_in,
                              void* d_out, int out_size, void* d_ws, size_t ws_size,
                              hipStream_t stream) {
  const float* x = (const float*)d_in[0];
  const int* srcp = (const int*)d_in[1];
  const int* dstp = (const int*)d_in[2];
  const float* Wl[3]  = {(const float*)d_in[3], (const float*)d_in[6], (const float*)d_in[9]};
  const float* alp[3] = {(const float*)d_in[4], (const float*)d_in[7], (const float*)d_in[10]};
  const float* arl[3] = {(const float*)d_in[5], (const float*)d_in[8], (const float*)d_in[11]};
  float* out = (float*)d_out;
  (void)in_sizes; (void)n_in; (void)out_size;

  auto rup = [](size_t b) { return (b + 255) & ~(size_t)255; };
  size_t sz_hin  = rup((size_t)NNODES * FDIM * 2);  // layer input buffer (K<=512)
  size_t sz_acc  = rup((size_t)NNODES * FDIM * 2);
  size_t sz_Wt   = rup((size_t)NREL * FDIM * FDIM * 2);
  size_t sz_int  = rup((size_t)NREL * NNODES * 4);
  size_t sz_csrc = rup((size_t)NREL * NEDGE * 4);
  size_t base_need = sz_hin + sz_acc + sz_Wt + 3 * sz_int + sz_csrc + rup(4096);
  size_t need_big   = base_need + rup((size_t)NNODES * 2048 * 2) + 2 * rup((size_t)NNODES * 32 * 4);
  size_t need_small = base_need + rup((size_t)NNODES * 512 * 2)  + 2 * rup((size_t)NNODES * 8 * 4);
  bool big;
  if (ws_size >= need_big) big = true;
  else if (ws_size >= need_small) big = false;
  else return;

  int nb = big ? 4 : 1;
  int nb4shift = big ? 4 : 2;
  int ncols = nb * FDIM;
  int nheads = nb * NH;

  char* ws = (char*)d_ws;
  size_t off = 0;
  auto alloc = [&](size_t bytes) -> void* { void* p = ws + off; off += rup(bytes); return p; };
  __bf16* hin  = (__bf16*)alloc((size_t)NNODES * FDIM * 2);   // layer input (hb)
  __bf16* accG = (__bf16*)alloc((size_t)NNODES * FDIM * 2);
  __bf16* fbuf = (__bf16*)alloc((size_t)NNODES * ncols * 2);
  float* el    = (float*)alloc((size_t)NNODES * nheads * 4);
  float* er    = (float*)alloc((size_t)NNODES * nheads * 4);
  __bf16* Wt   = (__bf16*)alloc((size_t)NREL * FDIM * FDIM * 2);
  int* deg  = (int*)alloc((size_t)NREL * NNODES * 4);
  int* ptrf = (int*)alloc((size_t)NREL * NNODES * 4);
  int* cur  = (int*)alloc((size_t)NREL * NNODES * 4);
  int* csrc = (int*)alloc((size_t)NREL * NEDGE * 4);
  int* bsum = (int*)alloc(4096);

  hipMemsetAsync(deg, 0, (size_t)NREL * NNODES * 4, stream);
  hipMemsetAsync(cur, 0, (size_t)NREL * NNODES * 4, stream);
  k_count<<<dim3((NEDGE + 255) / 256, NREL), 256, 0, stream>>>(dstp, deg);
  int ntot = NREL * NNODES;
  int nb1 = (ntot + 1023) / 1024;
  k_scan_a<<<nb1, 256, 0, stream>>>(deg, ptrf, bsum, ntot);
  k_scan_b<<<1, 256, 0, stream>>>(bsum, nb1);
  k_scan_c<<<(ntot + 255) / 256, 256, 0, stream>>>(ptrf, bsum, ntot);
  k_scatter<<<dim3((NEDGE + 255) / 256, NREL), 256, 0, stream>>>(srcp, dstp, ptrf, cur, csrc);

  for (int L = 0; L < 3; L++) {
    int K = (L == 0) ? 256 : FDIM;
    // layer input -> hin (decoupled from accG so aggs can overwrite accG)
    if (L == 0) k_conv<<<(NNODES * 256) / 1024, 256, 0, stream>>>(x, hin);
    else        k_copyb<<<(NNODES * 512) / 2048, 256, 0, stream>>>(accG, hin);
    k_transW<<<dim3(K / 32, 16, NREL), dim3(32, 8), 0, stream>>>(Wl[L], Wt, K);
    hipMemsetAsync(accG, 0, (size_t)NNODES * FDIM * 2, stream);
    int ngrid = NMB * 4 * nb;  // 3128 or 12512, both % 8 == 0
    int cpx = ngrid / 8;
    for (int g = 0; g < NREL / nb; g++) {
      k_gemm<<<ngrid, 256, 0, stream>>>(hin, Wt + (size_t)g * nb * FDIM * K, fbuf,
                                        alp[L] + g * nb * 512, arl[L] + g * nb * 512,
                                        el, er, NNODES, K, nb4shift, cpx);
      for (int q = 0; q < nb; q++) {
        int r = g * nb + q;
        k_agg<<<NNODES / 4, 256, 0, stream>>>(fbuf, el, er, ptrf + r * NNODES,
                                              deg + r * NNODES, csrc, accG,
                                              ncols, q * FDIM, nheads, q * NH);
      }
    }
  }
  k_mean<<<(NNODES * 64) / 256, 256, 0, stream>>>(accG, out);
}

// Round 7
// 2209.953 us; speedup vs baseline: 1.0895x; 1.0055x over previous
//
#include <hip/hip_runtime.h>
#include <hip/hip_bf16.h>
#include <math.h>

#define NNODES 100000
#define NREL 4
#define NEDGE 200000
#define NH 8
#define FDIM 512
#define NMB 782  // ceil(100000/128)

typedef float f4 __attribute__((ext_vector_type(4)));
typedef __bf16 bf16x8 __attribute__((ext_vector_type(8)));
typedef __bf16 bf16x4 __attribute__((ext_vector_type(4)));

__device__ __forceinline__ float eluf(float v) { return v > 0.f ? v : expm1f(v); }
__device__ __forceinline__ void gload16(const __bf16* g, __bf16* l) {
  __builtin_amdgcn_global_load_lds((const __attribute__((address_space(1))) void*)g,
                                   (__attribute__((address_space(3))) void*)l, 16, 0, 0);
}

// ---- f32 -> bf16 convert (count multiple of 1024) ----
__global__ void k_conv(const float* __restrict__ in, __bf16* __restrict__ outp) {
  int i = (blockIdx.x * 256 + threadIdx.x) * 4;
  f4 v = *(const f4*)(in + i);
  bf16x4 o = {(__bf16)v.x, (__bf16)v.y, (__bf16)v.z, (__bf16)v.w};
  *(bf16x4*)(outp + i) = o;
}

// ---- W [R,K,512] f32 -> Wt [R*512, K] bf16 (transposed) ----
__global__ void k_transW(const float* __restrict__ W, __bf16* __restrict__ Wt, int K) {
  __shared__ float tile[32][33];
  int r = blockIdx.z;
  const float* Wr = W + (size_t)r * K * FDIM;
  __bf16* Wtr = Wt + (size_t)r * FDIM * K;
  int k0 = blockIdx.x * 32, n0 = blockIdx.y * 32;
  int tx = threadIdx.x, ty = threadIdx.y;
  for (int i = ty; i < 32; i += 8)
    tile[i][tx] = Wr[(size_t)(k0 + i) * FDIM + n0 + tx];
  __syncthreads();
  for (int i = ty; i < 32; i += 8)
    Wtr[(size_t)(n0 + i) * K + k0 + tx] = (__bf16)tile[tx][i];
}

// ---- bf16 MFMA GEMM, 128x256 tile (0.56 KB LDS traffic per MFMA), 2-buffer
//      counted-vmcnt, bijective XCD swizzle, k-chunk XOR anti-conflict swizzle,
//      fused el/er epilogue. C[M, 256<<nnbsh] = A[M,K] * BT[.,K]^T ----
__global__ __launch_bounds__(256, 2) void k_gemm(const __bf16* __restrict__ A,
                                                 const __bf16* __restrict__ BT,
                                                 __bf16* __restrict__ C,
                                                 const float* __restrict__ al,
                                                 const float* __restrict__ ar,
                                                 float* __restrict__ el,
                                                 float* __restrict__ er, int M, int K,
                                                 int nnbsh) {
  __shared__ alignas(16) __bf16 lA[2][128 * 32];
  __shared__ alignas(16) __bf16 lB[2][256 * 32];
  int t = threadIdx.x, l = t & 63, w = t >> 6;
  // bijective XCD-chunked swizzle (m204): works for any gridDim
  int nwg = gridDim.x, q = nwg >> 3, r8 = nwg & 7;
  int x = blockIdx.x & 7, loc = blockIdx.x >> 3;
  int swz = (x < r8 ? x * (q + 1) : r8 * (q + 1) + (x - r8) * q) + loc;
  int nnbm = (1 << nnbsh) - 1;
  int m0 = (swz >> nnbsh) * 128, n0 = (swz & nnbm) * 256;
  int NDIM = 256 << nnbsh;
  int nh_tot = 4 << nnbsh;
  int wm = (w >> 1) * 64, wn = (w & 1) * 128;
  f4 acc[4][8] = {};

  // staging assignment: slot s -> row s>>2, LDS chunk s&3; source col chunk (s&3)^((s>>2)&3)
  const __bf16* pA[2];
  const __bf16* pB[4];
#pragma unroll
  for (int u = 0; u < 2; u++) {
    int s = t + u * 256;
    int row = m0 + (s >> 2); if (row >= M) row = M - 1;
    pA[u] = A + (size_t)row * K + (((s & 3) ^ ((s >> 2) & 3)) * 8);
  }
#pragma unroll
  for (int u = 0; u < 4; u++) {
    int s = t + u * 256;
    pB[u] = BT + (size_t)(n0 + (s >> 2)) * K + (((s & 3) ^ ((s >> 2) & 3)) * 8);
  }

#define STAGE(buf, kk)                                      \
  do {                                                      \
    gload16(pA[0] + (kk), &lA[buf][t * 8]);                 \
    gload16(pA[1] + (kk), &lA[buf][(t + 256) * 8]);         \
    gload16(pB[0] + (kk), &lB[buf][t * 8]);                 \
    gload16(pB[1] + (kk), &lB[buf][(t + 256) * 8]);         \
    gload16(pB[2] + (kk), &lB[buf][(t + 512) * 8]);         \
    gload16(pB[3] + (kk), &lB[buf][(t + 768) * 8]);         \
  } while (0)

  int nt = K >> 5;  // 8 or 16
  STAGE(0, 0);
  STAGE(1, 32);
  int segoff = ((l >> 4) ^ (l & 3)) * 8;   // anti-conflict read swizzle
  int rofA = (wm + (l & 15)) * 32 + segoff;
  int rofB = (wn + (l & 15)) * 32 + segoff;
  for (int kt = 0; kt < nt; kt++) {
    int cur = kt & 1;
    if (kt + 1 < nt) asm volatile("s_waitcnt vmcnt(6)" ::: "memory");
    else             asm volatile("s_waitcnt vmcnt(0)" ::: "memory");
    __builtin_amdgcn_s_barrier();  // tile kt landed
    bf16x8 a[4], b[8];
#pragma unroll
    for (int i = 0; i < 4; i++) a[i] = *(const bf16x8*)(&lA[cur][rofA + i * 512]);
#pragma unroll
    for (int j = 0; j < 8; j++) b[j] = *(const bf16x8*)(&lB[cur][rofB + j * 512]);
    asm volatile("s_waitcnt lgkmcnt(0)" ::: "memory");
    __builtin_amdgcn_s_barrier();  // all waves done reading buf cur (WAR safe)
    if (kt + 2 < nt) STAGE(cur, (kt + 2) * 32);  // restage under MFMA
#pragma unroll
    for (int i = 0; i < 4; i++)
#pragma unroll
      for (int j = 0; j < 8; j++)
        acc[i][j] = __builtin_amdgcn_mfma_f32_16x16x32_bf16(a[i], b[j], acc[i][j], 0, 0, 0);
  }
#undef STAGE

  // ---- C write (bf16) ----
  int cn = n0 + wn + (l & 15);
  int rbase = m0 + wm + (l >> 4) * 4;
#pragma unroll
  for (int i = 0; i < 4; i++)
#pragma unroll
    for (int q2 = 0; q2 < 4; q2++) {
      int row = rbase + i * 16 + q2;
      if (row < M) {
#pragma unroll
        for (int j = 0; j < 8; j++)
          C[(size_t)row * NDIM + cn + j * 16] = (__bf16)acc[i][j][q2];
      }
    }

  // ---- fused el/er: wave covers 2 heads (128 cols) ----
  int hbase = (n0 + wn) >> 6;
  float av[8], bv[8];
#pragma unroll
  for (int j = 0; j < 8; j++) {
    int h = hbase + (j >> 2);
    av[j] = al[h * 64 + (j & 3) * 16 + (l & 15)];
    bv[j] = ar[h * 64 + (j & 3) * 16 + (l & 15)];
  }
#pragma unroll
  for (int i = 0; i < 4; i++)
#pragma unroll
    for (int q2 = 0; q2 < 4; q2++) {
#pragma unroll
      for (int half = 0; half < 2; half++) {
        float se = acc[i][half * 4 + 0][q2] * av[half * 4 + 0] +
                   acc[i][half * 4 + 1][q2] * av[half * 4 + 1] +
                   acc[i][half * 4 + 2][q2] * av[half * 4 + 2] +
                   acc[i][half * 4 + 3][q2] * av[half * 4 + 3];
        float sr = acc[i][half * 4 + 0][q2] * bv[half * 4 + 0] +
                   acc[i][half * 4 + 1][q2] * bv[half * 4 + 1] +
                   acc[i][half * 4 + 2][q2] * bv[half * 4 + 2] +
                   acc[i][half * 4 + 3][q2] * bv[half * 4 + 3];
        se += __shfl_xor(se, 1); se += __shfl_xor(se, 2);
        se += __shfl_xor(se, 4); se += __shfl_xor(se, 8);
        sr += __shfl_xor(sr, 1); sr += __shfl_xor(sr, 2);
        sr += __shfl_xor(sr, 4); sr += __shfl_xor(sr, 8);
        if ((l & 15) == 0) {
          int row = rbase + i * 16 + q2;
          if (row < M) {
            int h = hbase + half;
            el[row * nh_tot + h] = se;
            er[row * nh_tot + h] = sr;
          }
        }
      }
    }
}

// ---- CSR build ----
__global__ void k_count(const int* __restrict__ dst, int* __restrict__ deg) {
  int e = blockIdx.x * 256 + threadIdx.x;
  int r = blockIdx.y;
  if (e < NEDGE) {
    int d = dst[(size_t)r * NEDGE + e];
    if ((unsigned)d < (unsigned)NNODES) atomicAdd(&deg[r * NNODES + d], 1);
  }
}

__global__ __launch_bounds__(256) void k_scan_a(const int* __restrict__ in, int* __restrict__ out,
                                                int* __restrict__ bsum, int n) {
  __shared__ int wsums[4];
  int t = threadIdx.x, lane = t & 63, w = t >> 6;
  int base = blockIdx.x * 1024 + t * 4;
  int v0 = base + 0 < n ? in[base + 0] : 0;
  int v1 = base + 1 < n ? in[base + 1] : 0;
  int v2 = base + 2 < n ? in[base + 2] : 0;
  int v3 = base + 3 < n ? in[base + 3] : 0;
  int tot = v0 + v1 + v2 + v3;
  int sc = tot;
#pragma unroll
  for (int off = 1; off < 64; off <<= 1) {
    int u = __shfl_up(sc, off);
    if (lane >= off) sc += u;
  }
  if (lane == 63) wsums[w] = sc;
  __syncthreads();
  int add = 0;
#pragma unroll
  for (int i = 0; i < 4; i++)
    if (i < w) add += wsums[i];
  int excl = add + sc - tot;
  if (base + 0 < n) out[base + 0] = excl;
  if (base + 1 < n) out[base + 1] = excl + v0;
  if (base + 2 < n) out[base + 2] = excl + v0 + v1;
  if (base + 3 < n) out[base + 3] = excl + v0 + v1 + v2;
  if (t == 255) bsum[blockIdx.x] = add + sc;
}

__global__ __launch_bounds__(256) void k_scan_b(int* __restrict__ bsum, int nb) {
  __shared__ int wsums[4];
  int t = threadIdx.x, lane = t & 63, w = t >> 6;
  int i0 = t * 2, i1 = t * 2 + 1;
  int v0 = i0 < nb ? bsum[i0] : 0;
  int v1 = i1 < nb ? bsum[i1] : 0;
  int tot = v0 + v1, sc = tot;
#pragma unroll
  for (int off = 1; off < 64; off <<= 1) {
    int u = __shfl_up(sc, off);
    if (lane >= off) sc += u;
  }
  if (lane == 63) wsums[w] = sc;
  __syncthreads();
  int add = 0;
#pragma unroll
  for (int i = 0; i < 4; i++)
    if (i < w) add += wsums[i];
  int excl = add + sc - tot;
  if (i0 < nb) bsum[i0] = excl;
  if (i1 < nb) bsum[i1] = excl + v0;
}

__global__ void k_scan_c(int* __restrict__ out, const int* __restrict__ bsum, int n) {
  int i = blockIdx.x * 256 + threadIdx.x;
  if (i < n) out[i] += bsum[i >> 10];
}

__global__ void k_scatter(const int* __restrict__ src, const int* __restrict__ dst,
                          const int* __restrict__ ptrf, int* __restrict__ cur,
                          int* __restrict__ csrc) {
  int e = blockIdx.x * 256 + threadIdx.x;
  int r = blockIdx.y;
  if (e >= NEDGE) return;
  int d = dst[(size_t)r * NEDGE + e];
  if ((unsigned)d >= (unsigned)NNODES) return;
  int slot = ptrf[r * NNODES + d] + atomicAdd(&cur[r * NNODES + d], 1);
  if ((unsigned)slot < (unsigned)(NREL * NEDGE))
    csrc[slot] = src[(size_t)r * NEDGE + e];
}

// ---- fused segment-softmax + aggregate + ELU, nrr relations per pass (one accG RMW) ----
__global__ void k_agg(const __bf16* __restrict__ f, const float* __restrict__ el,
                      const float* __restrict__ er, const int* __restrict__ ptrf,
                      const int* __restrict__ deg, const int* __restrict__ csrc,
                      __bf16* __restrict__ accG, int fstride, int estride, int nrr) {
  int t = threadIdx.x;
  int l = t & 63;
  int d = blockIdx.x * 4 + (t >> 6);
  int h = l >> 3;
  float res[8] = {0.f, 0.f, 0.f, 0.f, 0.f, 0.f, 0.f, 0.f};
  bool touched = false;
  for (int rr = 0; rr < nrr; rr++) {
    int cnt = deg[rr * NNODES + d];
    if (cnt <= 0) continue;
    touched = true;
    int start = ptrf[rr * NNODES + d];
    if (start < 0) start = 0;
    if (start > NREL * NEDGE) start = NREL * NEDGE;
    if (cnt > NREL * NEDGE - start) cnt = NREL * NEDGE - start;
    int eoff = rr * NH + h;
    int coff = rr * FDIM + l * 8;
    float erh = er[d * estride + eoff];
    float a[8] = {0.f, 0.f, 0.f, 0.f, 0.f, 0.f, 0.f, 0.f};
    float den = 0.f;
    for (int j = 0; j < cnt; j++) {
      int s = csrc[start + j];
      if ((unsigned)s >= (unsigned)NNODES) s = 0;
      float e = el[s * estride + eoff] + erh;
      e = (e > 0.f) ? e : 0.2f * e;
      float ex = __expf(e);
      den += ex;
      bf16x8 fv = *(const bf16x8*)(f + (size_t)s * fstride + coff);
#pragma unroll
      for (int i = 0; i < 8; i++) a[i] += ex * (float)fv[i];
    }
    float inv = 1.f / (den + 1e-9f);
#pragma unroll
    for (int i = 0; i < 8; i++) res[i] += eluf(a[i] * inv);
  }
  if (!touched) return;
  __bf16* ap = accG + (size_t)d * FDIM + l * 8;
  bf16x8 cv = *(bf16x8*)ap;
  bf16x8 o;
#pragma unroll
  for (int i = 0; i < 8; i++) o[i] = (__bf16)((float)cv[i] + res[i]);
  *(bf16x8*)ap = o;
}

// ---- final mean over heads ----
__global__ void k_mean(const __bf16* __restrict__ acc, float* __restrict__ out) {
  int t = blockIdx.x * 256 + threadIdx.x;
  int n = t >> 6, o = t & 63;
  const __bf16* ap = acc + (size_t)n * FDIM + o;
  float s = 0.f;
#pragma unroll
  for (int h = 0; h < 8; h++) s += (float)ap[h * 64];
  out[t] = s * 0.125f;
}

// ---- host ----
extern "C" void kernel_launch(void* const* d_in, const int* in_sizes, int n_in,
                              void* d_out, int out_size, void* d_ws, size_t ws_size,
                              hipStream_t stream) {
  const float* x = (const float*)d_in[0];
  const int* srcp = (const int*)d_in[1];
  const int* dstp = (const int*)d_in[2];
  const float* Wl[3]  = {(const float*)d_in[3], (const float*)d_in[6], (const float*)d_in[9]};
  const float* alp[3] = {(const float*)d_in[4], (const float*)d_in[7], (const float*)d_in[10]};
  const float* arl[3] = {(const float*)d_in[5], (const float*)d_in[8], (const float*)d_in[11]};
  float* out = (float*)d_out;
  (void)in_sizes; (void)n_in; (void)out_size;

  auto rup = [](size_t b) { return (b + 255) & ~(size_t)255; };
  size_t sz_buf  = rup((size_t)NNODES * FDIM * 2);           // 102.4 MB (x2: ping-pong)
  size_t sz_Wt   = rup((size_t)NREL * FDIM * FDIM * 2);
  size_t sz_int  = rup((size_t)NREL * NNODES * 4);
  size_t sz_csrc = rup((size_t)NREL * NEDGE * 4);
  size_t fixed = 2 * sz_buf + sz_Wt + 3 * sz_int + sz_csrc + rup(4096);
  size_t need2 = fixed + rup((size_t)NNODES * 1024 * 2) + 2 * rup((size_t)NNODES * 16 * 4);
  size_t need1 = fixed + rup((size_t)NNODES * 512 * 2)  + 2 * rup((size_t)NNODES * 8 * 4);
  int nb;
  if (ws_size >= need2) nb = 2;
  else if (ws_size >= need1) nb = 1;
  else return;  // diagnostic: zeros out, no crash

  int NDIM = nb * FDIM;
  int nheads = nb * NH;
  int nnbsh = (nb == 2) ? 2 : 1;  // n-256-blocks per batch = 4 or 2

  char* ws = (char*)d_ws;
  size_t off = 0;
  auto alloc = [&](size_t bytes) -> void* { void* p = ws + off; off += rup(bytes); return p; };
  __bf16* bufA = (__bf16*)alloc((size_t)NNODES * FDIM * 2);
  __bf16* bufB = (__bf16*)alloc((size_t)NNODES * FDIM * 2);
  __bf16* fbuf = (__bf16*)alloc((size_t)NNODES * NDIM * 2);
  float* el    = (float*)alloc((size_t)NNODES * nheads * 4);
  float* er    = (float*)alloc((size_t)NNODES * nheads * 4);
  __bf16* Wt   = (__bf16*)alloc((size_t)NREL * FDIM * FDIM * 2);
  int* deg  = (int*)alloc((size_t)NREL * NNODES * 4);
  int* ptrf = (int*)alloc((size_t)NREL * NNODES * 4);
  int* cur  = (int*)alloc((size_t)NREL * NNODES * 4);
  int* csrc = (int*)alloc((size_t)NREL * NEDGE * 4);
  int* bsum = (int*)alloc(4096);

  // ---- CSR by dst ----
  hipMemsetAsync(deg, 0, (size_t)NREL * NNODES * 4, stream);
  hipMemsetAsync(cur, 0, (size_t)NREL * NNODES * 4, stream);
  k_count<<<dim3((NEDGE + 255) / 256, NREL), 256, 0, stream>>>(dstp, deg);
  int ntot = NREL * NNODES;
  int nb1 = (ntot + 1023) / 1024;
  k_scan_a<<<nb1, 256, 0, stream>>>(deg, ptrf, bsum, ntot);
  k_scan_b<<<1, 256, 0, stream>>>(bsum, nb1);
  k_scan_c<<<(ntot + 255) / 256, 256, 0, stream>>>(ptrf, bsum, ntot);
  k_scatter<<<dim3((NEDGE + 255) / 256, NREL), 256, 0, stream>>>(srcp, dstp, ptrf, cur, csrc);

  k_conv<<<(NNODES * 256) / 1024, 256, 0, stream>>>(x, bufA);  // layer-0 input

  __bf16* inb = bufA;
  __bf16* outb = bufB;
  for (int L = 0; L < 3; L++) {
    int K = (L == 0) ? 256 : FDIM;
    k_transW<<<dim3(K / 32, 16, NREL), dim3(32, 8), 0, stream>>>(Wl[L], Wt, K);
    hipMemsetAsync(outb, 0, (size_t)NNODES * FDIM * 2, stream);
    int ngrid = NMB * (NDIM / 256);  // 1564 (nb=1) or 3128 (nb=2)
    for (int g = 0; g < NREL / nb; g++) {
      k_gemm<<<ngrid, 256, 0, stream>>>(inb, Wt + (size_t)g * nb * FDIM * K, fbuf,
                                        alp[L] + (size_t)g * nb * 512,
                                        arl[L] + (size_t)g * nb * 512,
                                        el, er, NNODES, K, nnbsh);
      k_agg<<<NNODES / 4, 256, 0, stream>>>(fbuf, el, er, ptrf + (size_t)g * nb * NNODES,
                                            deg + (size_t)g * nb * NNODES, csrc, outb,
                                            NDIM, nheads, nb);
    }
    __bf16* tmp = inb; inb = outb; outb = tmp;
  }
  // after 3 swaps, final accumulator is in inb
  k_mean<<<(NNODES * 64) / 256, 256, 0, stream>>>(inb, out);
}